// Round 5
// baseline (502.918 us; speedup 1.0000x reference)
//
#include <hip/hip_runtime.h>
#include <math.h>

#define EPS 1e-6f
#define NB 4096
#define NN 64

typedef __attribute__((ext_vector_type(8))) short short8_t;
typedef __attribute__((ext_vector_type(4))) short short4_t;
typedef __attribute__((ext_vector_type(4))) float f32x4;

__device__ __forceinline__ unsigned short f2bf(float x) {
  unsigned u = __float_as_uint(x);
  u = u + 0x7fffu + ((u >> 16) & 1u);
  return (unsigned short)(u >> 16);
}

// ---------------------------------------------------------------------------
// Pre-gather weights into MFMA fragment-major images (bf16 hi/lo planes).
// W1F: [p][MT 0..15][ks 0..3][lane][j]  (k>=114 zero-padded), plane stride 32768
// W2F: [p][MT 0..7 ][ks 0..7][lane][j],                        plane stride 32768
// value = W[m = MT*16 + (l&15)][k = ks*32 + (l>>4)*8 + j]
// Vectorized: one short8 (16B) store per plane per thread; 8192 threads.
// ---------------------------------------------------------------------------
__global__ __launch_bounds__(256)
void w_prep_kernel(const float* __restrict__ W1,
                   const float* __restrict__ W2,
                   short* __restrict__ W1F,
                   short* __restrict__ W2F) {
  int t = blockIdx.x * blockDim.x + threadIdx.x;
  if (t < 4096) {
    int l = t & 63, ks = (t >> 6) & 3, mt = t >> 8;  // mt 0..15
    int m = mt * 16 + (l & 15);
    int k0 = ks * 32 + (l >> 4) * 8;
    short8_t hi, lo;
#pragma unroll
    for (int j = 0; j < 8; j++) {
      int k = k0 + j;
      float x = (k < 114) ? W1[m * 114 + k] : 0.0f;
      unsigned u = __float_as_uint(x);
      hi[j] = (short)(unsigned short)(u >> 16);
      lo[j] = (short)f2bf(x - __uint_as_float(u & 0xFFFF0000u));
    }
    int base = ((mt * 4 + ks) * 64 + l) * 8;
    *(short8_t*)&W1F[base] = hi;
    *(short8_t*)&W1F[32768 + base] = lo;
  } else if (t < 8192) {
    int t2 = t - 4096;
    int l = t2 & 63, ks = (t2 >> 6) & 7, mt = t2 >> 9;  // mt 0..7
    int m = mt * 16 + (l & 15);
    int k0 = ks * 32 + (l >> 4) * 8;
    short8_t hi, lo;
#pragma unroll
    for (int j = 0; j < 8; j++) {
      float x = W2[m * 256 + k0 + j];
      unsigned u = __float_as_uint(x);
      hi[j] = (short)(unsigned short)(u >> 16);
      lo[j] = (short)f2bf(x - __uint_as_float(u & 0xFFFF0000u));
    }
    int base = ((mt * 8 + ks) * 64 + l) * 8;
    *(short8_t*)&W2F[base] = hi;
    *(short8_t*)&W2F[32768 + base] = lo;
  }
}

// ---------------------------------------------------------------------------
// Er net: 8 threads per batch row, 32 batches per 256-thread block.
// ---------------------------------------------------------------------------
__global__ __launch_bounds__(256)
void er_kernel(const float* __restrict__ ego_y,
               const float* __restrict__ W_sel, const float* __restrict__ b_sel,
               const float* __restrict__ W_s0,  const float* __restrict__ b_s0,
               const float* __restrict__ W_map, const float* __restrict__ b_map,
               const float* __restrict__ W_efc, const float* __restrict__ b_efc,
               float* __restrict__ out) {
  __shared__ float sm[470];
  const int tid = threadIdx.x;
  for (int i = tid; i < 470; i += 256) {
    float v;
    if (i < 384) v = W_map[i];
    else if (i < 392) v = b_map[i - 384];
    else if (i < 408) v = W_sel[i - 392];
    else if (i < 412) v = b_sel[i - 408];
    else if (i < 444) v = W_s0[i - 412];
    else if (i < 452) v = b_s0[i - 444];
    else if (i < 468) v = W_efc[i - 452];
    else v = b_efc[i - 468];
    sm[i] = v;
  }
  __syncthreads();
  const float* sWmap = sm;
  const float* sbmap = sm + 384;
  const float* sWsel = sm + 392;
  const float* sbsel = sm + 408;
  const float* sWs0  = sm + 412;
  const float* sbs0  = sm + 444;
  const float* sWefc = sm + 452;
  const float* sbefc = sm + 468;

  const int b = blockIdx.x * 32 + (tid >> 3);
  const int sub = tid & 7;
  const float lane[4] = {13.55f, 17.45f, 21.12f, 24.91f};
  float ego = ego_y[b];
  float dy[4];
#pragma unroll
  for (int j = 0; j < 4; j++) dy[j] = lane[j] - ego;

  float t[4];
#pragma unroll
  for (int i = 0; i < 4; i++) {
    float a = sbsel[i];
#pragma unroll
    for (int j = 0; j < 4; j++) a = fmaf(sWsel[i * 4 + j], dy[j], a);
    t[i] = a;
  }
  float m = fmaxf(fmaxf(t[0], t[1]), fmaxf(t[2], t[3]));
  float e[4], s = 0.f;
#pragma unroll
  for (int i = 0; i < 4; i++) { e[i] = expf(t[i] - m); s += e[i]; }
  float x[4];
#pragma unroll
  for (int i = 0; i < 4; i++) x[i] = (e[i] / s) * dy[i];

  float f[48];
  float sn[8];
#pragma unroll
  for (int k = 0; k < 8; k++) {
    float a = sbs0[k];
#pragma unroll
    for (int j = 0; j < 4; j++) a = fmaf(sWs0[k * 4 + j], x[j], a);
    sn[k] = sinf(a) + EPS;
  }
#pragma unroll
  for (int i = 0; i < 4; i++) f[i] = x[i];
#pragma unroll
  for (int k = 0; k < 8; k++) f[4 + k] = sn[k];
#pragma unroll
  for (int i = 0; i < 4; i++) {
    float q = x[i] * x[i] + EPS;
    f[12 + i] = q; f[36 + i] = 1.0f / q;
  }
#pragma unroll
  for (int i = 0; i < 4; i++) {
    float c3 = (x[i] * x[i]) * x[i] + EPS;
    f[16 + i] = c3; f[40 + i] = 1.0f / c3;
  }
#pragma unroll
  for (int i = 0; i < 4; i++) {
    float ex = expf(x[i]) + EPS;
    f[20 + i] = ex; f[44 + i] = 1.0f / ex;
  }
#pragma unroll
  for (int i = 0; i < 4; i++) f[24 + i] = 1.0f / (x[i] + EPS);
#pragma unroll
  for (int k = 0; k < 8; k++) f[28 + k] = 1.0f / sn[k];

  float a = sbmap[sub];
#pragma unroll
  for (int k = 0; k < 48; k++) a = fmaf(sWmap[sub * 48 + k], f[k], a);
  float y = fmaxf(a, 0.1f * a);

  float t0 = sWefc[0 * 8 + sub] * y;
  float t1 = sWefc[1 * 8 + sub] * y;
#pragma unroll
  for (int off = 4; off > 0; off >>= 1) {
    t0 += __shfl_xor(t0, off);
    t1 += __shfl_xor(t1, off);
  }
  if (sub == 0) {
    out[b * 4 + 0] = t0 + sbefc[0];
    out[b * 4 + 1] = t1 + sbefc[1];
  }
}

// ---------------------------------------------------------------------------
// En net: one block (512 thr, 8 waves) per batch. bf16 hi/lo 3-pass MFMA.
// LDS union buffer uni[2][64*256] (64KB):
//   phase A (features/L1): fea view, row stride 128 shorts, idx=r*128+(k^rsw)
//   phase B (h1/L2):       h1 view, row stride 256 shorts, idx=r*256+(o^rsw)
//   rsw = (r&7)<<3 (bank byte bits 4-6)
// L3 folded into L2 epilogue in-register; en_part[4][64][2] cross-wave.
// 68KB LDS total -> 2 blocks/CU.
// ---------------------------------------------------------------------------
__global__ __launch_bounds__(512, 4)
void en_kernel(const float* __restrict__ Pn, const float* __restrict__ Pego,
               const float* __restrict__ Vn, const float* __restrict__ Vego,
               const float* __restrict__ Cn,
               const float* __restrict__ W_s1, const float* __restrict__ b_s1,
               const float* __restrict__ b1, const float* __restrict__ b2,
               const float* __restrict__ W3, const float* __restrict__ b3,
               const float* __restrict__ Ww, const float* __restrict__ bw,
               const short* __restrict__ W1F, const short* __restrict__ W2F,
               float* __restrict__ out) {
  __shared__ __align__(16) short uni[2][64 * 256];
  __shared__ float stash[4 * 64];
  __shared__ float w3s[256];
  __shared__ float en_part[4][64][2];

  const int b = blockIdx.x;
  const int tid = threadIdx.x;
  const int w = tid >> 6;   // wave 0..7
  const int l = tid & 63;
  const int lr = l & 15;    // fragment row/col index
  const int lq = l >> 4;    // k-quad
  const int ntb = (w >> 2) * 2;  // this wave's row-tile base (2 tiles)

  // ---- issue W1 fragment loads early (hidden under feature build) ----
  short8_t w1f[2][4][4];  // [plane][m][ks]
#pragma unroll
  for (int p = 0; p < 2; p++)
#pragma unroll
    for (int m = 0; m < 4; m++)
#pragma unroll
      for (int ks = 0; ks < 4; ks++)
        w1f[p][m][ks] = *(const short8_t*)
            &W1F[p * 32768 + ((((w & 3) * 4 + m) * 4 + ks) * 64 + l) * 8];

  if (tid < 256) w3s[tid] = W3[tid];

  // ---------------- phase 0: features, wave-specialized, lane = row ----------
  // k-groups of 8 (P base 0, V base 7):  g0 base, g1 sin0-7, g2 sin8-15,
  // g3 {sin16,q0,q1,c30,c31,ex0,ex1,invd0}, g4 {invd1, invsin0-6},
  // g5 invsin7-14, g6 {invsin15,invsin16, invq0,invq1,invc30,invc31,invex0,invex1}
  // g14 {cn0,cn1,0..}, g15 zeros.  All writes: 2x short8 (b128), 8x fewer instrs.
  {
    const int r = l;
    const int rsw = (r & 7) << 3;
    auto putg = [&](int g, const float* v) {
      short8_t hi, lo;
#pragma unroll
      for (int i = 0; i < 8; i++) {
        unsigned u = __float_as_uint(v[i]);
        hi[i] = (short)(unsigned short)(u >> 16);
        lo[i] = (short)f2bf(v[i] - __uint_as_float(u & 0xFFFF0000u));
      }
      int idx = r * 128 + ((g * 8) ^ rsw);
      *(short8_t*)&uni[0][idx] = hi;
      *(short8_t*)&uni[1][idx] = lo;
    };
    if (w == 6) {
      const float2 p2 = ((const float2*)Pn)[b * NN + r];
      float e0 = Pego[b * 2 + 0], e1 = Pego[b * 2 + 1];
      stash[0 * 64 + r] = p2.x; stash[1 * 64 + r] = p2.y;
      stash[2 * 64 + r] = p2.x - e0; stash[3 * 64 + r] = p2.y - e1;
      const float2 cn = ((const float2*)Cn)[b * NN + r];
      float g14[8] = {cn.x, cn.y, 0.f, 0.f, 0.f, 0.f, 0.f, 0.f};
      float g15[8] = {0.f, 0.f, 0.f, 0.f, 0.f, 0.f, 0.f, 0.f};
      putg(14, g14);
      putg(15, g15);
    } else if (w < 6) {
      const bool isV = (w >= 3);
      const int role = isV ? (w - 3) : w;
      const int gb = isV ? 7 : 0;
      const float2 p2 = ((const float2*)(isV ? Vn : Pn))[b * NN + r];
      const float* Eb = isV ? Vego : Pego;
      float e0 = Eb[b * 2 + 0], e1 = Eb[b * 2 + 1];
      float d0 = p2.x - e0, d1 = p2.y - e1;
      if (role == 0) {
        float a15 = fmaf(W_s1[30], d0, fmaf(W_s1[31], d1, b_s1[15]));
        float a16 = fmaf(W_s1[32], d0, fmaf(W_s1[33], d1, b_s1[16]));
        float s15 = sinf(a15) + EPS, s16 = sinf(a16) + EPS;
        float q0 = d0 * d0 + EPS, q1 = d1 * d1 + EPS;
        float c30 = (d0 * d0) * d0 + EPS, c31 = (d1 * d1) * d1 + EPS;
        float ex0 = expf(d0) + EPS, ex1 = expf(d1) + EPS;
        float g0[8] = {e0, e1, p2.x, p2.y, d0, d1, d0, d1};
        float g3[8] = {s16, q0, q1, c30, c31, ex0, ex1, 1.0f / (d0 + EPS)};
        float g6[8] = {1.0f / s15, 1.0f / s16, 1.0f / q0, 1.0f / q1,
                       1.0f / c30, 1.0f / c31, 1.0f / ex0, 1.0f / ex1};
        putg(gb + 0, g0);
        putg(gb + 3, g3);
        putg(gb + 6, g6);
      } else if (role == 1) {
        float s[8];
#pragma unroll
        for (int i = 0; i < 8; i++) {
          float a = fmaf(W_s1[2 * i], d0, fmaf(W_s1[2 * i + 1], d1, b_s1[i]));
          s[i] = sinf(a) + EPS;
        }
        float g1[8] = {s[0], s[1], s[2], s[3], s[4], s[5], s[6], s[7]};
        float g4[8] = {1.0f / (d1 + EPS), 1.0f / s[0], 1.0f / s[1], 1.0f / s[2],
                       1.0f / s[3], 1.0f / s[4], 1.0f / s[5], 1.0f / s[6]};
        putg(gb + 1, g1);
        putg(gb + 4, g4);
      } else {
        float s[9];  // sins 7..15
#pragma unroll
        for (int i = 0; i < 9; i++) {
          float a = fmaf(W_s1[2 * (7 + i)], d0,
                         fmaf(W_s1[2 * (7 + i) + 1], d1, b_s1[7 + i]));
          s[i] = sinf(a) + EPS;
        }
        float g2[8] = {s[1], s[2], s[3], s[4], s[5], s[6], s[7], s[8]};
        float g5[8] = {1.0f / s[0], 1.0f / s[1], 1.0f / s[2], 1.0f / s[3],
                       1.0f / s[4], 1.0f / s[5], 1.0f / s[6], 1.0f / s[7]};
        putg(gb + 2, g2);
        putg(gb + 5, g5);
      }
    }
    // w == 7: no feature work
  }
  __syncthreads();

  // ---------------- layer 1: [256 o] x [64 r], K=128 (4m x 2n) ----------------
  f32x4 acc1[4][2];
#pragma unroll
  for (int m = 0; m < 4; m++)
#pragma unroll
    for (int n = 0; n < 2; n++) acc1[m][n] = (f32x4)0.0f;

#pragma unroll
  for (int ks = 0; ks < 4; ks++) {
    short8_t bh[2], bl[2];
#pragma unroll
    for (int n = 0; n < 2; n++) {
      int rr = (ntb + n) * 16 + lr;
      int idx = rr * 128 + ((ks * 32 + lq * 8) ^ ((rr & 7) << 3));
      bh[n] = *(const short8_t*)&uni[0][idx];
      bl[n] = *(const short8_t*)&uni[1][idx];
    }
    __builtin_amdgcn_s_setprio(1);
#pragma unroll
    for (int m = 0; m < 4; m++)
#pragma unroll
      for (int n = 0; n < 2; n++)
        acc1[m][n] = __builtin_amdgcn_mfma_f32_16x16x32_bf16(
            w1f[0][m][ks], bh[n], acc1[m][n], 0, 0, 0);
#pragma unroll
    for (int m = 0; m < 4; m++)
#pragma unroll
      for (int n = 0; n < 2; n++)
        acc1[m][n] = __builtin_amdgcn_mfma_f32_16x16x32_bf16(
            w1f[0][m][ks], bl[n], acc1[m][n], 0, 0, 0);
#pragma unroll
    for (int m = 0; m < 4; m++)
#pragma unroll
      for (int n = 0; n < 2; n++)
        acc1[m][n] = __builtin_amdgcn_mfma_f32_16x16x32_bf16(
            w1f[1][m][ks], bh[n], acc1[m][n], 0, 0, 0);
    __builtin_amdgcn_s_setprio(0);
  }

  // ---- issue W2 fragment loads (w1f dead; latency spans barrier+epilogue) ----
  short8_t w2f[2][2][8];  // [plane][m][ks]
#pragma unroll
  for (int p = 0; p < 2; p++)
#pragma unroll
    for (int m = 0; m < 2; m++)
#pragma unroll
      for (int ks = 0; ks < 8; ks++)
        w2f[p][m][ks] = *(const short8_t*)
            &W2F[p * 32768 + ((((w & 3) * 2 + m) * 8 + ks) * 64 + l) * 8];

  // all fea reads done before h1 overwrites the union buffer
  __syncthreads();

  // ---- L1 epilogue: bias + leaky + trunc hi/lo split -> h1 view ----
#pragma unroll
  for (int m = 0; m < 4; m++) {
    int o0 = ((w & 3) * 4 + m) * 16 + lq * 4;
    f32x4 bb = *(const f32x4*)&b1[o0];
#pragma unroll
    for (int n = 0; n < 2; n++) {
      int rr = (ntb + n) * 16 + lr;
      short4_t hq, lo4;
#pragma unroll
      for (int i = 0; i < 4; i++) {
        float v = acc1[m][n][i] + bb[i];
        v = fmaxf(v, 0.1f * v);
        unsigned u = __float_as_uint(v);
        hq[i] = (short)(unsigned short)(u >> 16);
        lo4[i] = (short)f2bf(v - __uint_as_float(u & 0xFFFF0000u));
      }
      int idx = rr * 256 + (o0 ^ ((rr & 7) << 3));
      *(short4_t*)&uni[0][idx] = hq;
      *(short4_t*)&uni[1][idx] = lo4;
    }
  }
  __syncthreads();

  // ---------------- layer 2: [128 o] x [64 r], K=256 (2m x 2n) ----------------
  f32x4 acc2[2][2];
#pragma unroll
  for (int m = 0; m < 2; m++)
#pragma unroll
    for (int n = 0; n < 2; n++) acc2[m][n] = (f32x4)0.0f;

#pragma unroll
  for (int ks = 0; ks < 8; ks++) {
    short8_t bh[2], bl[2];
#pragma unroll
    for (int n = 0; n < 2; n++) {
      int rr = (ntb + n) * 16 + lr;
      int idx = rr * 256 + ((ks * 32 + lq * 8) ^ ((rr & 7) << 3));
      bh[n] = *(const short8_t*)&uni[0][idx];
      bl[n] = *(const short8_t*)&uni[1][idx];
    }
    __builtin_amdgcn_s_setprio(1);
#pragma unroll
    for (int m = 0; m < 2; m++)
#pragma unroll
      for (int n = 0; n < 2; n++)
        acc2[m][n] = __builtin_amdgcn_mfma_f32_16x16x32_bf16(
            w2f[0][m][ks], bh[n], acc2[m][n], 0, 0, 0);
#pragma unroll
    for (int m = 0; m < 2; m++)
#pragma unroll
      for (int n = 0; n < 2; n++)
        acc2[m][n] = __builtin_amdgcn_mfma_f32_16x16x32_bf16(
            w2f[0][m][ks], bl[n], acc2[m][n], 0, 0, 0);
#pragma unroll
    for (int m = 0; m < 2; m++)
#pragma unroll
      for (int n = 0; n < 2; n++)
        acc2[m][n] = __builtin_amdgcn_mfma_f32_16x16x32_bf16(
            w2f[1][m][ks], bh[n], acc2[m][n], 0, 0, 0);
    __builtin_amdgcn_s_setprio(0);
  }

  // ---- L2 epilogue fused with layer 3 (in-register W3 dot) ----
  {
    f32x4 w3v[2][2];  // [c][m]
#pragma unroll
    for (int c = 0; c < 2; c++)
#pragma unroll
      for (int m = 0; m < 2; m++)
        w3v[c][m] = *(const f32x4*)
            &w3s[c * 128 + ((w & 3) * 2 + m) * 16 + lq * 4];

    float p00 = 0.f, p01 = 0.f, p10 = 0.f, p11 = 0.f;  // p[c][n]
#pragma unroll
    for (int m = 0; m < 2; m++) {
      int o0 = ((w & 3) * 2 + m) * 16 + lq * 4;
      f32x4 bb = *(const f32x4*)&b2[o0];
#pragma unroll
      for (int i = 0; i < 4; i++) {
        float u0 = acc2[m][0][i] + bb[i];
        u0 = fmaxf(u0, 0.1f * u0);
        float u1 = acc2[m][1][i] + bb[i];
        u1 = fmaxf(u1, 0.1f * u1);
        p00 = fmaf(u0, w3v[0][m][i], p00);
        p10 = fmaf(u0, w3v[1][m][i], p10);
        p01 = fmaf(u1, w3v[0][m][i], p01);
        p11 = fmaf(u1, w3v[1][m][i], p11);
      }
    }
    // sum the 4 lq-groups: lanes l, l^16, l^32, l^48 share lr (same row)
#pragma unroll
    for (int off = 16; off < 64; off <<= 1) {
      p00 += __shfl_xor(p00, off);
      p01 += __shfl_xor(p01, off);
      p10 += __shfl_xor(p10, off);
      p11 += __shfl_xor(p11, off);
    }
    if (l < 16) {
      en_part[w & 3][ntb * 16 + l][0] = p00;
      en_part[w & 3][ntb * 16 + l][1] = p10;
      en_part[w & 3][(ntb + 1) * 16 + l][0] = p01;
      en_part[w & 3][(ntb + 1) * 16 + l][1] = p11;
    }
  }
  __syncthreads();

  // ---------------- logits + softmax over neighbors + reduce ----------------
  if (tid < 64) {
    const int r = tid;
    float E0 = b3[0] + en_part[0][r][0] + en_part[1][r][0] +
               en_part[2][r][0] + en_part[3][r][0];
    float E1 = b3[1] + en_part[0][r][1] + en_part[1][r][1] +
               en_part[2][r][1] + en_part[3][r][1];
    float pn0 = stash[0 * 64 + r], pn1 = stash[1 * 64 + r];
    float dp0 = stash[2 * 64 + r], dp1 = stash[3 * 64 + r];
    float logit = bw[0];
    logit = fmaf(E0, Ww[0], logit);
    logit = fmaf(E1, Ww[1], logit);
    logit = fmaf(pn0, Ww[2], logit);
    logit = fmaf(pn1, Ww[3], logit);
    logit = fmaf(dp0, Ww[4], logit);
    logit = fmaf(dp1, Ww[5], logit);
    float m = logit;
#pragma unroll
    for (int off = 32; off > 0; off >>= 1) m = fmaxf(m, __shfl_xor(m, off));
    float e = expf(logit - m);
    float ssum = e;
#pragma unroll
    for (int off = 32; off > 0; off >>= 1) ssum += __shfl_xor(ssum, off);
    float wgt = e / ssum;
    float o0 = wgt * E0, o1 = wgt * E1;
#pragma unroll
    for (int off = 32; off > 0; off >>= 1) {
      o0 += __shfl_xor(o0, off);
      o1 += __shfl_xor(o1, off);
    }
    if (r == 0) {
      out[b * 4 + 2] = o0;
      out[b * 4 + 3] = o1;
    }
  }
}

// ---------------------------------------------------------------------------
extern "C" void kernel_launch(void* const* d_in, const int* in_sizes, int n_in,
                              void* d_out, int out_size, void* d_ws, size_t ws_size,
                              hipStream_t stream) {
  const float* ego_y = (const float*)d_in[0];
  const float* Pn    = (const float*)d_in[1];
  const float* Pego  = (const float*)d_in[2];
  const float* Vn    = (const float*)d_in[3];
  const float* Vego  = (const float*)d_in[4];
  const float* Cn    = (const float*)d_in[5];
  const float* W_sel = (const float*)d_in[6];
  const float* b_sel = (const float*)d_in[7];
  const float* W_s0  = (const float*)d_in[8];
  const float* b_s0  = (const float*)d_in[9];
  const float* W_map = (const float*)d_in[10];
  const float* b_map = (const float*)d_in[11];
  const float* W_efc = (const float*)d_in[12];
  const float* b_efc = (const float*)d_in[13];
  const float* W_s1  = (const float*)d_in[14];
  const float* b_s1  = (const float*)d_in[15];
  const float* W1    = (const float*)d_in[16];
  const float* b1    = (const float*)d_in[17];
  const float* W2    = (const float*)d_in[18];
  const float* b2    = (const float*)d_in[19];
  const float* W3    = (const float*)d_in[20];
  const float* b3    = (const float*)d_in[21];
  const float* Ww    = (const float*)d_in[22];
  const float* bw    = (const float*)d_in[23];
  float* out = (float*)d_out;

  short* W1F = (short*)d_ws;          // 2 planes x 32768 shorts = 128 KB
  short* W2F = W1F + 65536;           // 2 planes x 32768 shorts = 128 KB

  w_prep_kernel<<<32, 256, 0, stream>>>(W1, W2, W1F, W2F);
  er_kernel<<<NB / 32, 256, 0, stream>>>(ego_y, W_sel, b_sel, W_s0, b_s0,
                                         W_map, b_map, W_efc, b_efc, out);
  en_kernel<<<NB, 512, 0, stream>>>(Pn, Pego, Vn, Vego, Cn, W_s1, b_s1,
                                    b1, b2, W3, b3, Ww, bw, W1F, W2F, out);
}

// Round 6
// 217.958 us; speedup vs baseline: 2.3074x; 2.3074x over previous
//
#include <hip/hip_runtime.h>
#include <math.h>

#define EPS 1e-6f
#define NB 4096
#define NN 64

typedef __attribute__((ext_vector_type(8))) short short8_t;
typedef __attribute__((ext_vector_type(4))) short short4_t;
typedef __attribute__((ext_vector_type(4))) float f32x4;

__device__ __forceinline__ unsigned short f2bf(float x) {
  unsigned u = __float_as_uint(x);
  u = u + 0x7fffu + ((u >> 16) & 1u);
  return (unsigned short)(u >> 16);
}

// ---------------------------------------------------------------------------
// Pre-gather weights into MFMA fragment-major images (bf16 hi/lo planes),
// via LDS staging: coalesced global reads + coalesced 16B stores.
// Block 0: W1 [256][114] -> W1F; Block 1: W2 [128][256] -> W2F.
// W1F: [p][MT 0..15][ks 0..3][lane][j]  (k>=114 zero-padded), plane stride 32768
// W2F: [p][MT 0..7 ][ks 0..7][lane][j],                        plane stride 32768
// value = W[m = MT*16 + (l&15)][k = ks*32 + (l>>4)*8 + j]
// ---------------------------------------------------------------------------
__global__ __launch_bounds__(512)
void w_prep_kernel(const float* __restrict__ W1,
                   const float* __restrict__ W2,
                   short* __restrict__ W1F,
                   short* __restrict__ W2F) {
  __shared__ float S[32768];  // 128 KB
  const int tid = threadIdx.x;
  if (blockIdx.x == 0) {
    for (int i = tid; i < 256 * 114; i += 512) S[i] = W1[i];
    __syncthreads();
    for (int u = tid; u < 4096; u += 512) {
      int l = u & 63, ks = (u >> 6) & 3, mt = u >> 8;
      int m = mt * 16 + (l & 15);
      int k0 = ks * 32 + (l >> 4) * 8;
      short8_t hi, lo;
#pragma unroll
      for (int j = 0; j < 8; j++) {
        int k = k0 + j;
        float x = (k < 114) ? S[m * 114 + k] : 0.0f;
        unsigned uu = __float_as_uint(x);
        hi[j] = (short)(unsigned short)(uu >> 16);
        lo[j] = (short)f2bf(x - __uint_as_float(uu & 0xFFFF0000u));
      }
      int base = ((mt * 4 + ks) * 64 + l) * 8;
      *(short8_t*)&W1F[base] = hi;
      *(short8_t*)&W1F[32768 + base] = lo;
    }
  } else {
    for (int i = tid; i < 128 * 256; i += 512) S[i] = W2[i];
    __syncthreads();
    for (int u = tid; u < 4096; u += 512) {
      int l = u & 63, ks = (u >> 6) & 7, mt = u >> 9;
      int m = mt * 16 + (l & 15);
      int k0 = ks * 32 + (l >> 4) * 8;
      short8_t hi, lo;
#pragma unroll
      for (int j = 0; j < 8; j++) {
        float x = S[m * 256 + k0 + j];
        unsigned uu = __float_as_uint(x);
        hi[j] = (short)(unsigned short)(uu >> 16);
        lo[j] = (short)f2bf(x - __uint_as_float(uu & 0xFFFF0000u));
      }
      int base = ((mt * 8 + ks) * 64 + l) * 8;
      *(short8_t*)&W2F[base] = hi;
      *(short8_t*)&W2F[32768 + base] = lo;
    }
  }
}

// ---------------------------------------------------------------------------
// En + Er fused: one block (512 thr, 8 waves) per batch.
// Waves 0-5: feature build; wave 6: stash/Cn/pad; wave 7 lanes 0-7: Er net.
// bf16 hi/lo 3-pass MFMA; weights streamed per-ks from ws (L2) — low VGPR.
// LDS union uni[2][64*256] (64KB): fea view (stride 128) then h1 view (256).
// rsw = (r&7)<<3 (bank byte bits 4-6). L3 folded into L2 epilogue.
// 68KB LDS + <=128 VGPR -> 2 blocks/CU.
// ---------------------------------------------------------------------------
__global__ __launch_bounds__(512, 4)
void en_kernel(const float* __restrict__ Pn, const float* __restrict__ Pego,
               const float* __restrict__ Vn, const float* __restrict__ Vego,
               const float* __restrict__ Cn,
               const float* __restrict__ W_s1, const float* __restrict__ b_s1,
               const float* __restrict__ b1, const float* __restrict__ b2,
               const float* __restrict__ W3, const float* __restrict__ b3,
               const float* __restrict__ Ww, const float* __restrict__ bw,
               const float* __restrict__ ego_y,
               const float* __restrict__ W_sel, const float* __restrict__ b_sel,
               const float* __restrict__ W_s0, const float* __restrict__ b_s0,
               const float* __restrict__ W_map, const float* __restrict__ b_map,
               const float* __restrict__ W_efc, const float* __restrict__ b_efc,
               const short* __restrict__ W1F, const short* __restrict__ W2F,
               float* __restrict__ out) {
  __shared__ __align__(16) short uni[2][64 * 256];
  __shared__ float stash[4 * 64];
  __shared__ float w3s[256];
  __shared__ float en_part[4][64][2];

  const int b = blockIdx.x;
  const int tid = threadIdx.x;
  const int w = tid >> 6;   // wave 0..7
  const int l = tid & 63;
  const int lr = l & 15;    // fragment row/col index
  const int lq = l >> 4;    // k-quad
  const int ntb = (w >> 2) * 2;  // this wave's row-tile base (2 tiles)

  if (tid < 256) w3s[tid] = W3[tid];

  // ---------------- phase 0: features / stash / Er, wave-specialized --------
  {
    const int r = l;
    const int rsw = (r & 7) << 3;
    auto putg = [&](int g, const float* v) {
      short8_t hi, lo;
#pragma unroll
      for (int i = 0; i < 8; i++) {
        unsigned u = __float_as_uint(v[i]);
        hi[i] = (short)(unsigned short)(u >> 16);
        lo[i] = (short)f2bf(v[i] - __uint_as_float(u & 0xFFFF0000u));
      }
      int idx = r * 128 + ((g * 8) ^ rsw);
      *(short8_t*)&uni[0][idx] = hi;
      *(short8_t*)&uni[1][idx] = lo;
    };
    if (w == 6) {
      const float2 p2 = ((const float2*)Pn)[b * NN + r];
      float e0 = Pego[b * 2 + 0], e1 = Pego[b * 2 + 1];
      stash[0 * 64 + r] = p2.x; stash[1 * 64 + r] = p2.y;
      stash[2 * 64 + r] = p2.x - e0; stash[3 * 64 + r] = p2.y - e1;
      const float2 cn = ((const float2*)Cn)[b * NN + r];
      float g14[8] = {cn.x, cn.y, 0.f, 0.f, 0.f, 0.f, 0.f, 0.f};
      float g15[8] = {0.f, 0.f, 0.f, 0.f, 0.f, 0.f, 0.f, 0.f};
      putg(14, g14);
      putg(15, g15);
    } else if (w < 6) {
      const bool isV = (w >= 3);
      const int role = isV ? (w - 3) : w;
      const int gb = isV ? 7 : 0;
      const float2 p2 = ((const float2*)(isV ? Vn : Pn))[b * NN + r];
      const float* Eb = isV ? Vego : Pego;
      float e0 = Eb[b * 2 + 0], e1 = Eb[b * 2 + 1];
      float d0 = p2.x - e0, d1 = p2.y - e1;
      if (role == 0) {
        float a15 = fmaf(W_s1[30], d0, fmaf(W_s1[31], d1, b_s1[15]));
        float a16 = fmaf(W_s1[32], d0, fmaf(W_s1[33], d1, b_s1[16]));
        float s15 = sinf(a15) + EPS, s16 = sinf(a16) + EPS;
        float q0 = d0 * d0 + EPS, q1 = d1 * d1 + EPS;
        float c30 = (d0 * d0) * d0 + EPS, c31 = (d1 * d1) * d1 + EPS;
        float ex0 = expf(d0) + EPS, ex1 = expf(d1) + EPS;
        float g0[8] = {e0, e1, p2.x, p2.y, d0, d1, d0, d1};
        float g3[8] = {s16, q0, q1, c30, c31, ex0, ex1, 1.0f / (d0 + EPS)};
        float g6[8] = {1.0f / s15, 1.0f / s16, 1.0f / q0, 1.0f / q1,
                       1.0f / c30, 1.0f / c31, 1.0f / ex0, 1.0f / ex1};
        putg(gb + 0, g0);
        putg(gb + 3, g3);
        putg(gb + 6, g6);
      } else if (role == 1) {
        float s[8];
#pragma unroll
        for (int i = 0; i < 8; i++) {
          float a = fmaf(W_s1[2 * i], d0, fmaf(W_s1[2 * i + 1], d1, b_s1[i]));
          s[i] = sinf(a) + EPS;
        }
        float g1[8] = {s[0], s[1], s[2], s[3], s[4], s[5], s[6], s[7]};
        float g4[8] = {1.0f / (d1 + EPS), 1.0f / s[0], 1.0f / s[1], 1.0f / s[2],
                       1.0f / s[3], 1.0f / s[4], 1.0f / s[5], 1.0f / s[6]};
        putg(gb + 1, g1);
        putg(gb + 4, g4);
      } else {
        float s[9];  // sins 7..15
#pragma unroll
        for (int i = 0; i < 9; i++) {
          float a = fmaf(W_s1[2 * (7 + i)], d0,
                         fmaf(W_s1[2 * (7 + i) + 1], d1, b_s1[7 + i]));
          s[i] = sinf(a) + EPS;
        }
        float g2[8] = {s[1], s[2], s[3], s[4], s[5], s[6], s[7], s[8]};
        float g5[8] = {1.0f / s[0], 1.0f / s[1], 1.0f / s[2], 1.0f / s[3],
                       1.0f / s[4], 1.0f / s[5], 1.0f / s[6], 1.0f / s[7]};
        putg(gb + 2, g2);
        putg(gb + 5, g5);
      }
    } else if (l < 8) {
      // ---- Er net, 8 lanes of wave 7 ----
      const int sub = l;
      const float lane4[4] = {13.55f, 17.45f, 21.12f, 24.91f};
      float ego = ego_y[b];
      float dy[4];
#pragma unroll
      for (int j = 0; j < 4; j++) dy[j] = lane4[j] - ego;
      float t[4];
#pragma unroll
      for (int i = 0; i < 4; i++) {
        float a = b_sel[i];
#pragma unroll
        for (int j = 0; j < 4; j++) a = fmaf(W_sel[i * 4 + j], dy[j], a);
        t[i] = a;
      }
      float m = fmaxf(fmaxf(t[0], t[1]), fmaxf(t[2], t[3]));
      float e[4], s = 0.f;
#pragma unroll
      for (int i = 0; i < 4; i++) { e[i] = expf(t[i] - m); s += e[i]; }
      float x[4];
#pragma unroll
      for (int i = 0; i < 4; i++) x[i] = (e[i] / s) * dy[i];
      float f[48];
      float sn[8];
#pragma unroll
      for (int k = 0; k < 8; k++) {
        float a = b_s0[k];
#pragma unroll
        for (int j = 0; j < 4; j++) a = fmaf(W_s0[k * 4 + j], x[j], a);
        sn[k] = sinf(a) + EPS;
      }
#pragma unroll
      for (int i = 0; i < 4; i++) f[i] = x[i];
#pragma unroll
      for (int k = 0; k < 8; k++) f[4 + k] = sn[k];
#pragma unroll
      for (int i = 0; i < 4; i++) {
        float q = x[i] * x[i] + EPS;
        f[12 + i] = q; f[36 + i] = 1.0f / q;
      }
#pragma unroll
      for (int i = 0; i < 4; i++) {
        float c3 = (x[i] * x[i]) * x[i] + EPS;
        f[16 + i] = c3; f[40 + i] = 1.0f / c3;
      }
#pragma unroll
      for (int i = 0; i < 4; i++) {
        float ex = expf(x[i]) + EPS;
        f[20 + i] = ex; f[44 + i] = 1.0f / ex;
      }
#pragma unroll
      for (int i = 0; i < 4; i++) f[24 + i] = 1.0f / (x[i] + EPS);
#pragma unroll
      for (int k = 0; k < 8; k++) f[28 + k] = 1.0f / sn[k];
      float a = b_map[sub];
#pragma unroll
      for (int k = 0; k < 48; k++) a = fmaf(W_map[sub * 48 + k], f[k], a);
      float y = fmaxf(a, 0.1f * a);
      float t0 = W_efc[sub] * y;
      float t1 = W_efc[8 + sub] * y;
#pragma unroll
      for (int off = 4; off > 0; off >>= 1) {
        t0 += __shfl_xor(t0, off);
        t1 += __shfl_xor(t1, off);
      }
      if (sub == 0) {
        out[b * 4 + 0] = t0 + b_efc[0];
        out[b * 4 + 1] = t1 + b_efc[1];
      }
    }
  }
  __syncthreads();

  // ---------------- layer 1: [256 o] x [64 r], K=128 (4m x 2n) ----------------
  // weights streamed per-ks: 8 frags (32 VGPR) live, compiler hoists to budget
  const short* w1b = W1F + (w & 3) * 4 * 4 * 512 + l * 8;  // frag(m,ks,p)
  f32x4 acc1[4][2];
#pragma unroll
  for (int m = 0; m < 4; m++)
#pragma unroll
    for (int n = 0; n < 2; n++) acc1[m][n] = (f32x4)0.0f;

#pragma unroll
  for (int ks = 0; ks < 4; ks++) {
    short8_t w1h[4], w1l[4];
#pragma unroll
    for (int m = 0; m < 4; m++) {
      w1h[m] = *(const short8_t*)&w1b[(m * 4 + ks) * 512];
      w1l[m] = *(const short8_t*)&w1b[32768 + (m * 4 + ks) * 512];
    }
    short8_t bh[2], bl[2];
#pragma unroll
    for (int n = 0; n < 2; n++) {
      int rr = (ntb + n) * 16 + lr;
      int idx = rr * 128 + ((ks * 32 + lq * 8) ^ ((rr & 7) << 3));
      bh[n] = *(const short8_t*)&uni[0][idx];
      bl[n] = *(const short8_t*)&uni[1][idx];
    }
    __builtin_amdgcn_s_setprio(1);
#pragma unroll
    for (int m = 0; m < 4; m++)
#pragma unroll
      for (int n = 0; n < 2; n++)
        acc1[m][n] = __builtin_amdgcn_mfma_f32_16x16x32_bf16(
            w1h[m], bh[n], acc1[m][n], 0, 0, 0);
#pragma unroll
    for (int m = 0; m < 4; m++)
#pragma unroll
      for (int n = 0; n < 2; n++)
        acc1[m][n] = __builtin_amdgcn_mfma_f32_16x16x32_bf16(
            w1h[m], bl[n], acc1[m][n], 0, 0, 0);
#pragma unroll
    for (int m = 0; m < 4; m++)
#pragma unroll
      for (int n = 0; n < 2; n++)
        acc1[m][n] = __builtin_amdgcn_mfma_f32_16x16x32_bf16(
            w1l[m], bh[n], acc1[m][n], 0, 0, 0);
    __builtin_amdgcn_s_setprio(0);
  }

  // all fea reads done before h1 overwrites the union buffer
  __syncthreads();

  // ---- L1 epilogue: bias + leaky + trunc hi/lo split -> h1 view ----
#pragma unroll
  for (int m = 0; m < 4; m++) {
    int o0 = ((w & 3) * 4 + m) * 16 + lq * 4;
    f32x4 bb = *(const f32x4*)&b1[o0];
#pragma unroll
    for (int n = 0; n < 2; n++) {
      int rr = (ntb + n) * 16 + lr;
      short4_t hq, lo4;
#pragma unroll
      for (int i = 0; i < 4; i++) {
        float v = acc1[m][n][i] + bb[i];
        v = fmaxf(v, 0.1f * v);
        unsigned u = __float_as_uint(v);
        hq[i] = (short)(unsigned short)(u >> 16);
        lo4[i] = (short)f2bf(v - __uint_as_float(u & 0xFFFF0000u));
      }
      int idx = rr * 256 + (o0 ^ ((rr & 7) << 3));
      *(short4_t*)&uni[0][idx] = hq;
      *(short4_t*)&uni[1][idx] = lo4;
    }
  }
  __syncthreads();

  // ---------------- layer 2: [128 o] x [64 r], K=256 (2m x 2n) ----------------
  const short* w2b = W2F + (w & 3) * 2 * 8 * 512 + l * 8;  // frag(m,ks,p)
  f32x4 acc2[2][2];
#pragma unroll
  for (int m = 0; m < 2; m++)
#pragma unroll
    for (int n = 0; n < 2; n++) acc2[m][n] = (f32x4)0.0f;

#pragma unroll
  for (int ks = 0; ks < 8; ks++) {
    short8_t w2h[2], w2l[2];
#pragma unroll
    for (int m = 0; m < 2; m++) {
      w2h[m] = *(const short8_t*)&w2b[(m * 8 + ks) * 512];
      w2l[m] = *(const short8_t*)&w2b[32768 + (m * 8 + ks) * 512];
    }
    short8_t bh[2], bl[2];
#pragma unroll
    for (int n = 0; n < 2; n++) {
      int rr = (ntb + n) * 16 + lr;
      int idx = rr * 256 + ((ks * 32 + lq * 8) ^ ((rr & 7) << 3));
      bh[n] = *(const short8_t*)&uni[0][idx];
      bl[n] = *(const short8_t*)&uni[1][idx];
    }
    __builtin_amdgcn_s_setprio(1);
#pragma unroll
    for (int m = 0; m < 2; m++)
#pragma unroll
      for (int n = 0; n < 2; n++)
        acc2[m][n] = __builtin_amdgcn_mfma_f32_16x16x32_bf16(
            w2h[m], bh[n], acc2[m][n], 0, 0, 0);
#pragma unroll
    for (int m = 0; m < 2; m++)
#pragma unroll
      for (int n = 0; n < 2; n++)
        acc2[m][n] = __builtin_amdgcn_mfma_f32_16x16x32_bf16(
            w2h[m], bl[n], acc2[m][n], 0, 0, 0);
#pragma unroll
    for (int m = 0; m < 2; m++)
#pragma unroll
      for (int n = 0; n < 2; n++)
        acc2[m][n] = __builtin_amdgcn_mfma_f32_16x16x32_bf16(
            w2l[m], bh[n], acc2[m][n], 0, 0, 0);
    __builtin_amdgcn_s_setprio(0);
  }

  // ---- L2 epilogue fused with layer 3 (in-register W3 dot) ----
  {
    f32x4 w3v[2][2];  // [c][m]
#pragma unroll
    for (int c = 0; c < 2; c++)
#pragma unroll
      for (int m = 0; m < 2; m++)
        w3v[c][m] = *(const f32x4*)
            &w3s[c * 128 + ((w & 3) * 2 + m) * 16 + lq * 4];

    float p00 = 0.f, p01 = 0.f, p10 = 0.f, p11 = 0.f;  // p[c][n]
#pragma unroll
    for (int m = 0; m < 2; m++) {
      int o0 = ((w & 3) * 2 + m) * 16 + lq * 4;
      f32x4 bb = *(const f32x4*)&b2[o0];
#pragma unroll
      for (int i = 0; i < 4; i++) {
        float u0 = acc2[m][0][i] + bb[i];
        u0 = fmaxf(u0, 0.1f * u0);
        float u1 = acc2[m][1][i] + bb[i];
        u1 = fmaxf(u1, 0.1f * u1);
        p00 = fmaf(u0, w3v[0][m][i], p00);
        p10 = fmaf(u0, w3v[1][m][i], p10);
        p01 = fmaf(u1, w3v[0][m][i], p01);
        p11 = fmaf(u1, w3v[1][m][i], p11);
      }
    }
    // sum the 4 lq-groups: lanes l, l^16, l^32, l^48 share lr (same row)
#pragma unroll
    for (int off = 16; off < 64; off <<= 1) {
      p00 += __shfl_xor(p00, off);
      p01 += __shfl_xor(p01, off);
      p10 += __shfl_xor(p10, off);
      p11 += __shfl_xor(p11, off);
    }
    if (l < 16) {
      en_part[w & 3][ntb * 16 + l][0] = p00;
      en_part[w & 3][ntb * 16 + l][1] = p10;
      en_part[w & 3][(ntb + 1) * 16 + l][0] = p01;
      en_part[w & 3][(ntb + 1) * 16 + l][1] = p11;
    }
  }
  __syncthreads();

  // ---------------- logits + softmax over neighbors + reduce ----------------
  if (tid < 64) {
    const int r = tid;
    float E0 = b3[0] + en_part[0][r][0] + en_part[1][r][0] +
               en_part[2][r][0] + en_part[3][r][0];
    float E1 = b3[1] + en_part[0][r][1] + en_part[1][r][1] +
               en_part[2][r][1] + en_part[3][r][1];
    float pn0 = stash[0 * 64 + r], pn1 = stash[1 * 64 + r];
    float dp0 = stash[2 * 64 + r], dp1 = stash[3 * 64 + r];
    float logit = bw[0];
    logit = fmaf(E0, Ww[0], logit);
    logit = fmaf(E1, Ww[1], logit);
    logit = fmaf(pn0, Ww[2], logit);
    logit = fmaf(pn1, Ww[3], logit);
    logit = fmaf(dp0, Ww[4], logit);
    logit = fmaf(dp1, Ww[5], logit);
    float m = logit;
#pragma unroll
    for (int off = 32; off > 0; off >>= 1) m = fmaxf(m, __shfl_xor(m, off));
    float e = expf(logit - m);
    float ssum = e;
#pragma unroll
    for (int off = 32; off > 0; off >>= 1) ssum += __shfl_xor(ssum, off);
    float wgt = e / ssum;
    float o0 = wgt * E0, o1 = wgt * E1;
#pragma unroll
    for (int off = 32; off > 0; off >>= 1) {
      o0 += __shfl_xor(o0, off);
      o1 += __shfl_xor(o1, off);
    }
    if (r == 0) {
      out[b * 4 + 2] = o0;
      out[b * 4 + 3] = o1;
    }
  }
}

// ---------------------------------------------------------------------------
extern "C" void kernel_launch(void* const* d_in, const int* in_sizes, int n_in,
                              void* d_out, int out_size, void* d_ws, size_t ws_size,
                              hipStream_t stream) {
  const float* ego_y = (const float*)d_in[0];
  const float* Pn    = (const float*)d_in[1];
  const float* Pego  = (const float*)d_in[2];
  const float* Vn    = (const float*)d_in[3];
  const float* Vego  = (const float*)d_in[4];
  const float* Cn    = (const float*)d_in[5];
  const float* W_sel = (const float*)d_in[6];
  const float* b_sel = (const float*)d_in[7];
  const float* W_s0  = (const float*)d_in[8];
  const float* b_s0  = (const float*)d_in[9];
  const float* W_map = (const float*)d_in[10];
  const float* b_map = (const float*)d_in[11];
  const float* W_efc = (const float*)d_in[12];
  const float* b_efc = (const float*)d_in[13];
  const float* W_s1  = (const float*)d_in[14];
  const float* b_s1  = (const float*)d_in[15];
  const float* W1    = (const float*)d_in[16];
  const float* b1    = (const float*)d_in[17];
  const float* W2    = (const float*)d_in[18];
  const float* b2    = (const float*)d_in[19];
  const float* W3    = (const float*)d_in[20];
  const float* b3    = (const float*)d_in[21];
  const float* Ww    = (const float*)d_in[22];
  const float* bw    = (const float*)d_in[23];
  float* out = (float*)d_out;

  short* W1F = (short*)d_ws;          // 2 planes x 32768 shorts = 128 KB
  short* W2F = W1F + 65536;           // 2 planes x 32768 shorts = 128 KB

  w_prep_kernel<<<2, 512, 0, stream>>>(W1, W2, W1F, W2F);
  en_kernel<<<NB, 512, 0, stream>>>(Pn, Pego, Vn, Vego, Cn, W_s1, b_s1,
                                    b1, b2, W3, b3, Ww, bw,
                                    ego_y, W_sel, b_sel, W_s0, b_s0,
                                    W_map, b_map, W_efc, b_efc,
                                    W1F, W2F, out);
}